// Round 2
// 698.990 us; speedup vs baseline: 1.2432x; 1.2432x over previous
//
#include <hip/hip_runtime.h>
#include <hip/hip_bf16.h>
#include <math.h>

typedef __hip_bfloat16 hbf16;
typedef __attribute__((ext_vector_type(8))) short bf16x8;
typedef __attribute__((ext_vector_type(4))) float f32x4;

constexpr int kD  = 1024;
constexpr int kP  = 512;
constexpr int kH  = 16;
constexpr int kFF = 4096;
constexpr int kHD = 64;
constexpr int kB  = 2;
constexpr int kL  = 1024;
constexpr int kTok = kB * kL;   // 2048

__device__ inline short f2bf(float x) { hbf16 h = __float2bfloat16(x); return *(short*)&h; }

// ---------------- weight transpose+convert: fp32 [K][N] -> bf16-bits [N][K] ----------------
__global__ __launch_bounds__(256) void transpose_bf16(
    const float* __restrict__ src, short* __restrict__ dst, int K, int N)
{
    __shared__ float t[32][33];
    int n0 = blockIdx.x * 32, k0 = blockIdx.y * 32;
    int tx = threadIdx.x & 31, ty = threadIdx.x >> 5;
    #pragma unroll
    for (int r = ty; r < 32; r += 8)
        t[r][tx] = src[(size_t)(k0 + r) * N + n0 + tx];
    __syncthreads();
    #pragma unroll
    for (int r = ty; r < 32; r += 8)
        dst[(size_t)(n0 + r) * K + k0 + tx] = f2bf(t[tx][r]);
}

// ---------------- bias broadcast fill: C[m][n] = bias[n] (N power of two) ----------------
__global__ __launch_bounds__(256) void bias_fill(
    const float* __restrict__ bias, float* __restrict__ C, int N, int total4)
{
    int i = blockIdx.x * 256 + threadIdx.x;
    if (i >= total4) return;
    int n = (i * 4) & (N - 1);
    *(float4*)&C[(size_t)i * 4] = *(const float4*)&bias[n];
}

// ---------------- concat up to 3 bias vectors of length n ----------------
__global__ void concat_bias(float* __restrict__ o, const float* __restrict__ a,
                            const float* __restrict__ b, const float* __restrict__ c, int n)
{
    int i = blockIdx.x * blockDim.x + threadIdx.x;
    if (i < n) o[i] = a[i];
    else if (i < 2 * n) { if (b) o[i] = b[i - n]; }
    else if (i < 3 * n) { if (c) o[i] = c[i - 2 * n]; }
}

// ---------------- MFMA GEMM with split-K (grid.z) + register prefetch ----------------
// ksplit==1: direct write, bias (+ optional gelu) fused.
// ksplit>1 : C must be pre-filled with bias; each split atomicAdds its partial.
constexpr int LDK = 40;
__global__ __launch_bounds__(256) void gemm_mfma(
    const float* __restrict__ A, const short* __restrict__ WT,
    const float* __restrict__ bias, float* __restrict__ C,
    int M, int N, int K, int act, int ksplit)
{
    __shared__ short As[128 * LDK];
    __shared__ short Bs[128 * LDK];
    const int tid = threadIdx.x;
    const int m0 = blockIdx.y * 128, n0 = blockIdx.x * 128;
    const int ks = K / ksplit;
    const int kbeg = blockIdx.z * ks, kend = kbeg + ks;
    const int wave = tid >> 6, lane = tid & 63;
    const int wm = (wave & 1) * 64, wn = (wave >> 1) * 64;
    const int l15 = lane & 15, quad = lane >> 4;

    // per-thread staging coordinates (row advances by e*32 / e*64)
    const int am = tid >> 3, akq = (tid & 7) * 4;
    const int bn = tid >> 2, bkg = (tid & 3) * 8;

    f32x4 acc[4][4];
    #pragma unroll
    for (int i = 0; i < 4; ++i)
        #pragma unroll
        for (int j = 0; j < 4; ++j)
            acc[i][j] = (f32x4){0.f, 0.f, 0.f, 0.f};

    // prologue: prefetch first tile into registers
    float4 ra[4];
    bf16x8 rb[2];
    #pragma unroll
    for (int e = 0; e < 4; ++e)
        ra[e] = *(const float4*)&A[(size_t)(m0 + am + e * 32) * K + kbeg + akq];
    #pragma unroll
    for (int e = 0; e < 2; ++e)
        rb[e] = *(const bf16x8*)&WT[(size_t)(n0 + bn + e * 64) * K + kbeg + bkg];

    for (int kk = kbeg; kk < kend; kk += 32) {
        // write staged registers -> LDS (convert A to bf16 here)
        #pragma unroll
        for (int e = 0; e < 4; ++e) {
            short4 s4 = make_short4(f2bf(ra[e].x), f2bf(ra[e].y), f2bf(ra[e].z), f2bf(ra[e].w));
            *(short4*)&As[(am + e * 32) * LDK + akq] = s4;
        }
        #pragma unroll
        for (int e = 0; e < 2; ++e)
            *(bf16x8*)&Bs[(bn + e * 64) * LDK + bkg] = rb[e];
        __syncthreads();

        // issue next tile's global loads now — latency hides under the MFMAs below
        if (kk + 32 < kend) {
            #pragma unroll
            for (int e = 0; e < 4; ++e)
                ra[e] = *(const float4*)&A[(size_t)(m0 + am + e * 32) * K + kk + 32 + akq];
            #pragma unroll
            for (int e = 0; e < 2; ++e)
                rb[e] = *(const bf16x8*)&WT[(size_t)(n0 + bn + e * 64) * K + kk + 32 + bkg];
        }

        bf16x8 af[4], bfr[4];
        #pragma unroll
        for (int i = 0; i < 4; ++i)
            af[i] = *(bf16x8*)&As[(wm + i * 16 + l15) * LDK + quad * 8];
        #pragma unroll
        for (int j = 0; j < 4; ++j)
            bfr[j] = *(bf16x8*)&Bs[(wn + j * 16 + l15) * LDK + quad * 8];
        #pragma unroll
        for (int i = 0; i < 4; ++i)
            #pragma unroll
            for (int j = 0; j < 4; ++j)
                acc[i][j] = __builtin_amdgcn_mfma_f32_16x16x32_bf16(af[i], bfr[j], acc[i][j], 0, 0, 0);
        __syncthreads();
    }

    #pragma unroll
    for (int j = 0; j < 4; ++j) {
        int n = n0 + wn + j * 16 + l15;
        if (ksplit == 1) {
            float bv = bias[n];
            #pragma unroll
            for (int i = 0; i < 4; ++i) {
                int mb = m0 + wm + i * 16 + quad * 4;
                #pragma unroll
                for (int r = 0; r < 4; ++r) {
                    float v = acc[i][j][r] + bv;
                    if (act) v = v * 0.5f * (1.0f + erff(v * 0.70710678118654752f));
                    C[(size_t)(mb + r) * N + n] = v;
                }
            }
        } else {
            #pragma unroll
            for (int i = 0; i < 4; ++i) {
                int mb = m0 + wm + i * 16 + quad * 4;
                #pragma unroll
                for (int r = 0; r < 4; ++r)
                    atomicAdd(&C[(size_t)(mb + r) * N + n], acc[i][j][r]);
            }
        }
    }
}

// ---------------- qk_pack: RoPE + optional scale + bf16 cast, [Tok,ldx] -> [b,h,l,64] ----------------
__global__ void qk_pack(const float* __restrict__ x, const float* __restrict__ pos,
                        short* __restrict__ outp, float scale, int ldx, int off)
{
    int idx = blockIdx.x * blockDim.x + threadIdx.x;
    if (idx >= kTok * kH * 32) return;
    int d = idx & 31;
    int h = (idx >> 5) & (kH - 1);
    int row = idx >> 9;
    int l = row & (kL - 1);
    int b = row >> 10;
    float a1 = pos[l * kHD + d];
    float a2 = pos[l * kHD + d + 32];
    size_t base = (size_t)row * ldx + off + h * kHD;
    float x1 = x[base + d], x2 = x[base + d + 32];
    float r1 = (x1 * cosf(a1) - x2 * sinf(a1)) * scale;
    float r2 = (x2 * cosf(a2) + x1 * sinf(a2)) * scale;
    size_t ob = ((size_t)(b * kH + h) * kL + l) * 64;
    outp[ob + d]      = f2bf(r1);
    outp[ob + d + 32] = f2bf(r2);
}

// ---------------- v_pack: transpose [Tok,ldx] fp32 -> [b,h,hd,l] bf16 ----------------
__global__ __launch_bounds__(256) void v_pack(const float* __restrict__ v, short* __restrict__ outp,
                                              int ldx, int off)
{
    int l0 = blockIdx.x * 64, h = blockIdx.y, b = blockIdx.z;
    __shared__ float t[64][65];
    int tid = threadIdx.x;
    #pragma unroll
    for (int e = 0; e < 4; ++e) {
        int idx = tid + e * 256;
        int r = idx >> 4, c4 = (idx & 15) * 4;
        const float4 vv = *(const float4*)&v[(size_t)(b * kL + l0 + r) * ldx + off + h * kHD + c4];
        t[r][c4] = vv.x; t[r][c4 + 1] = vv.y; t[r][c4 + 2] = vv.z; t[r][c4 + 3] = vv.w;
    }
    __syncthreads();
    int hd = tid >> 2, seg = (tid & 3) * 16;
    size_t ob = ((size_t)(b * kH + h) * 64 + hd) * kL + l0 + seg;
    short tmp[16];
    #pragma unroll
    for (int i = 0; i < 16; ++i) tmp[i] = f2bf(t[seg + i][hd]);
    #pragma unroll
    for (int i = 0; i < 16; i += 4)
        *(short4*)&outp[ob + i] = make_short4(tmp[i], tmp[i + 1], tmp[i + 2], tmp[i + 3]);
}

// ---------------- MFMA flash attention ----------------
constexpr int AQ = 64, AK = 64;
constexpr int QLD = 72;   // shorts/row = 144 B (16B-aligned)
constexpr int PLD = 68;   // floats/row for P
__global__ __launch_bounds__(256) void attn_mfma(
    const short* __restrict__ qpk, const short* __restrict__ kpk,
    const short* __restrict__ vpk, const float* __restrict__ alibi,
    const int* __restrict__ mask, float* __restrict__ out)
{
    const int q0 = blockIdx.x * AQ, h = blockIdx.y, b = blockIdx.z;
    const int tid = threadIdx.x, wave = tid >> 6, lane = tid & 63;
    const int l15 = lane & 15, quad = lane >> 4;
    __shared__ short Qs[AQ * QLD];
    __shared__ short Ks[AK * QLD];
    __shared__ short Vt[kHD * QLD];
    __shared__ float Ps[AQ * PLD];

    const short* qbase = qpk + ((size_t)(b * kH + h) * kL) * 64;
    const short* kbase = kpk + ((size_t)(b * kH + h) * kL) * 64;
    const short* vbase = vpk + ((size_t)(b * kH + h) * 64) * kL;

    #pragma unroll
    for (int e = 0; e < 2; ++e) {
        int idx = tid + e * 256;
        int r = idx >> 3, c8 = (idx & 7) * 8;
        *(bf16x8*)&Qs[r * QLD + c8] = *(const bf16x8*)&qbase[(size_t)(q0 + r) * 64 + c8];
    }
    float mst[4], lst[4];
    #pragma unroll
    for (int r = 0; r < 4; ++r) { mst[r] = -3e38f; lst[r] = 0.f; }
    f32x4 oacc[4];
    #pragma unroll
    for (int j = 0; j < 4; ++j) oacc[j] = (f32x4){0.f, 0.f, 0.f, 0.f};
    __syncthreads();

    for (int k0 = 0; k0 < kL; k0 += AK) {
        #pragma unroll
        for (int e = 0; e < 2; ++e) {
            int idx = tid + e * 256;
            int r = idx >> 3, c8 = (idx & 7) * 8;
            *(bf16x8*)&Ks[r * QLD + c8] = *(const bf16x8*)&kbase[(size_t)(k0 + r) * 64 + c8];
            *(bf16x8*)&Vt[r * QLD + c8] = *(const bf16x8*)&vbase[(size_t)r * kL + k0 + c8];
        }
        __syncthreads();

        bf16x8 aq[2];
        #pragma unroll
        for (int s = 0; s < 2; ++s)
            aq[s] = *(bf16x8*)&Qs[(wave * 16 + l15) * QLD + s * 32 + quad * 8];
        f32x4 sacc[4];
        #pragma unroll
        for (int nt = 0; nt < 4; ++nt) sacc[nt] = (f32x4){0.f, 0.f, 0.f, 0.f};
        #pragma unroll
        for (int nt = 0; nt < 4; ++nt)
            #pragma unroll
            for (int s = 0; s < 2; ++s) {
                bf16x8 bk = *(bf16x8*)&Ks[(nt * 16 + l15) * QLD + s * 32 + quad * 8];
                sacc[nt] = __builtin_amdgcn_mfma_f32_16x16x32_bf16(aq[s], bk, sacc[nt], 0, 0, 0);
            }

        float sv[4][4];
        float mx[4] = {-3e38f, -3e38f, -3e38f, -3e38f};
        #pragma unroll
        for (int nt = 0; nt < 4; ++nt) {
            int key = k0 + nt * 16 + l15;
            int mk = mask[b * kL + key];
            #pragma unroll
            for (int r = 0; r < 4; ++r) {
                int qrow = q0 + wave * 16 + quad * 4 + r;
                float al = alibi[((size_t)h * kL + qrow) * kL + key];
                float s = mk ? -1e30f : sacc[nt][r];
                s += al;
                sv[nt][r] = s;
                mx[r] = fmaxf(mx[r], s);
            }
        }
        #pragma unroll
        for (int m = 1; m <= 8; m <<= 1)
            #pragma unroll
            for (int r = 0; r < 4; ++r)
                mx[r] = fmaxf(mx[r], __shfl_xor(mx[r], m));
        float alpha[4], lsum[4];
        #pragma unroll
        for (int r = 0; r < 4; ++r) {
            float mn = fmaxf(mst[r], mx[r]);
            alpha[r] = __expf(mst[r] - mn);
            mst[r] = mn;
            lsum[r] = 0.f;
        }
        #pragma unroll
        for (int nt = 0; nt < 4; ++nt)
            #pragma unroll
            for (int r = 0; r < 4; ++r) {
                float p = __expf(sv[nt][r] - mst[r]);
                sv[nt][r] = p;
                lsum[r] += p;
            }
        #pragma unroll
        for (int m = 1; m <= 8; m <<= 1)
            #pragma unroll
            for (int r = 0; r < 4; ++r)
                lsum[r] += __shfl_xor(lsum[r], m);
        #pragma unroll
        for (int r = 0; r < 4; ++r) lst[r] = lst[r] * alpha[r] + lsum[r];

        #pragma unroll
        for (int nt = 0; nt < 4; ++nt)
            #pragma unroll
            for (int r = 0; r < 4; ++r)
                Ps[(wave * 16 + quad * 4 + r) * PLD + nt * 16 + l15] = sv[nt][r];
        #pragma unroll
        for (int j = 0; j < 4; ++j)
            #pragma unroll
            for (int r = 0; r < 4; ++r)
                oacc[j][r] *= alpha[r];
        __syncthreads();

        #pragma unroll
        for (int s = 0; s < 2; ++s) {
            const float* pr = &Ps[(wave * 16 + l15) * PLD + s * 32 + quad * 8];
            float4 p0 = *(const float4*)&pr[0];
            float4 p1 = *(const float4*)&pr[4];
            bf16x8 ap;
            ap[0] = f2bf(p0.x); ap[1] = f2bf(p0.y); ap[2] = f2bf(p0.z); ap[3] = f2bf(p0.w);
            ap[4] = f2bf(p1.x); ap[5] = f2bf(p1.y); ap[6] = f2bf(p1.z); ap[7] = f2bf(p1.w);
            #pragma unroll
            for (int j = 0; j < 4; ++j) {
                bf16x8 bv = *(bf16x8*)&Vt[(j * 16 + l15) * QLD + s * 32 + quad * 8];
                oacc[j] = __builtin_amdgcn_mfma_f32_16x16x32_bf16(ap, bv, oacc[j], 0, 0, 0);
            }
        }
        __syncthreads();
    }

    #pragma unroll
    for (int j = 0; j < 4; ++j)
        #pragma unroll
        for (int r = 0; r < 4; ++r) {
            int qrow = q0 + wave * 16 + quad * 4 + r;
            out[(size_t)(b * kL + qrow) * kD + h * kHD + j * 16 + l15] = oacc[j][r] / lst[r];
        }
}

// ---------------- out = res + LayerNorm(z) ----------------
__global__ __launch_bounds__(256) void add_ln(
    const float* __restrict__ res, const float* __restrict__ z,
    const float* __restrict__ g, const float* __restrict__ bi,
    float* __restrict__ out)
{
    int row = blockIdx.x, tid = threadIdx.x;
    __shared__ float red[256], red2[256];
    const float* zr = z + (size_t)row * kD;
    float s = 0.f, sq = 0.f;
    for (int i = tid; i < kD; i += 256) { float vv = zr[i]; s += vv; sq += vv * vv; }
    red[tid] = s; red2[tid] = sq; __syncthreads();
    for (int st = 128; st > 0; st >>= 1) {
        if (tid < st) { red[tid] += red[tid + st]; red2[tid] += red2[tid + st]; }
        __syncthreads();
    }
    float mean = red[0] / kD;
    float var = red2[0] / kD - mean * mean;
    float rstd = rsqrtf(var + 1e-5f);
    for (int i = tid; i < kD; i += 256) {
        float vv = (zr[i] - mean) * rstd * g[i] + bi[i];
        out[(size_t)row * kD + i] = res[(size_t)row * kD + i] + vv;
    }
}

// ---------------- out = LayerNorm(res + f) ----------------
__global__ __launch_bounds__(256) void ln_final(
    const float* __restrict__ res, const float* __restrict__ f,
    const float* __restrict__ g, const float* __restrict__ bi,
    float* __restrict__ out)
{
    int row = blockIdx.x, tid = threadIdx.x;
    __shared__ float tt[kD];
    __shared__ float red[256], red2[256];
    float s = 0.f, sq = 0.f;
    for (int i = tid; i < kD; i += 256) {
        float vv = res[(size_t)row * kD + i] + f[(size_t)row * kD + i];
        tt[i] = vv; s += vv; sq += vv * vv;
    }
    red[tid] = s; red2[tid] = sq; __syncthreads();
    for (int st = 128; st > 0; st >>= 1) {
        if (tid < st) { red[tid] += red[tid + st]; red2[tid] += red2[tid + st]; }
        __syncthreads();
    }
    float mean = red[0] / kD;
    float var = red2[0] / kD - mean * mean;
    float rstd = rsqrtf(var + 1e-5f);
    for (int i = tid; i < kD; i += 256)
        out[(size_t)row * kD + i] = (tt[i] - mean) * rstd * g[i] + bi[i];
}

extern "C" void kernel_launch(void* const* d_in, const int* in_sizes, int n_in,
                              void* d_out, int out_size, void* d_ws, size_t ws_size,
                              hipStream_t stream)
{
    const float* memory      = (const float*)d_in[0];
    const float* tgt         = (const float*)d_in[1];
    const float* self_alibi  = (const float*)d_in[2];
    const float* self_pos    = (const float*)d_in[3];
    const float* cross_alibi = (const float*)d_in[4];
    const float* cross_pos   = (const float*)d_in[5];
    const int*   mask        = (const int*)d_in[6];
    const float* sa_lat_w = (const float*)d_in[7];   const float* sa_lat_b = (const float*)d_in[8];
    const float* sa_q_w   = (const float*)d_in[9];   const float* sa_q_b   = (const float*)d_in[10];
    const float* sa_k_w   = (const float*)d_in[11];  const float* sa_k_b   = (const float*)d_in[12];
    const float* sa_v_w   = (const float*)d_in[13];  const float* sa_v_b   = (const float*)d_in[14];
    const float* sa_out_w = (const float*)d_in[15];  const float* sa_out_b = (const float*)d_in[16];
    const float* ca_lat_w = (const float*)d_in[17];  const float* ca_lat_b = (const float*)d_in[18];
    const float* ca_q_w   = (const float*)d_in[19];  const float* ca_q_b   = (const float*)d_in[20];
    const float* ca_k_w   = (const float*)d_in[21];  const float* ca_k_b   = (const float*)d_in[22];
    const float* ca_v_w   = (const float*)d_in[23];  const float* ca_v_b   = (const float*)d_in[24];
    const float* ca_out_w = (const float*)d_in[25];  const float* ca_out_b = (const float*)d_in[26];
    const float* lin1_w   = (const float*)d_in[27];  const float* lin1_b   = (const float*)d_in[28];
    const float* lin2_w   = (const float*)d_in[29];  const float* lin2_b   = (const float*)d_in[30];
    const float* n1_g = (const float*)d_in[31];  const float* n1_b = (const float*)d_in[32];
    const float* n2_g = (const float*)d_in[33];  const float* n2_b = (const float*)d_in[34];
    const float* n3_g = (const float*)d_in[35];  const float* n3_b = (const float*)d_in[36];

    // workspace: 15M floats = 60 MB (same footprint as before)
    const size_t M1 = 1u << 20;
    float* W     = (float*)d_ws;
    float* xb    = W + 0 * M1;    // 2M — residual stream
    float* tmp   = W + 2 * M1;    // 2M — pre-LN tensor (free during attention)
    float* proj  = W + 4 * M1;    // 1M — latent projection
    float* qkvb  = W + 5 * M1;    // 6M — fused qkv [2048][3072]; cross: qb=+0 (2M), kvb=+2M (4M)
    float* attnb = W + 11 * M1;   // 2M
    float* ffh   = W + 4 * M1;    // 8M — FFN hidden, overlays proj/qkvb/attnb-low
    short* wslot = (short*)(W + 13 * M1);  // 4M shorts
    float* bcat  = W + 11 * M1;   // bias concat scratch (attnb region, dead at use time)
    // packed bf16 buffers overlay dead fp32 regions during attention:
    short* qpk = (short*)(W + 2 * M1);   // 2M shorts over tmp[0:1M]
    short* kpk = (short*)(W + 3 * M1);   // 2M shorts over tmp[1M:2M]
    short* vpk = (short*)(W + 4 * M1);   // 2M shorts over proj (dead after kv gemm)

    auto gemm = [&](const float* A, const float* Wt, const float* bias, float* C,
                    int M, int N, int K, int act, int S) {
        transpose_bf16<<<dim3(N / 32, K / 32), dim3(256), 0, stream>>>(Wt, wslot, K, N);
        if (S > 1)
            bias_fill<<<dim3(M * N / 1024), dim3(256), 0, stream>>>(bias, C, N, M * N / 4);
        gemm_mfma<<<dim3(N / 128, M / 128, S), dim3(256), 0, stream>>>(A, wslot, bias, C, M, N, K, act, S);
    };
    dim3 agrid(kL / AQ, kH, kB);
    dim3 vgrid(kL / 64, kH, kB);
    dim3 tgD(kD / 32, kP / 32);   // transpose grid for [kP][kD] weights

    // ---- self attention ----
    gemm(tgt, sa_lat_w, sa_lat_b, proj, kTok, kP, kD, 0, 4);
    // fused q|k|v: WT rows [0,1024)=q, [1024,2048)=k, [2048,3072)=v
    transpose_bf16<<<tgD, dim3(256), 0, stream>>>(sa_q_w, wslot, kP, kD);
    transpose_bf16<<<tgD, dim3(256), 0, stream>>>(sa_k_w, wslot + (size_t)kD * kP, kP, kD);
    transpose_bf16<<<tgD, dim3(256), 0, stream>>>(sa_v_w, wslot + (size_t)2 * kD * kP, kP, kD);
    concat_bias<<<dim3(12), dim3(256), 0, stream>>>(bcat, sa_q_b, sa_k_b, sa_v_b, kD);
    gemm_mfma<<<dim3(3 * kD / 128, kTok / 128, 1), dim3(256), 0, stream>>>(
        proj, wslot, bcat, qkvb, kTok, 3 * kD, kP, 0, 1);
    qk_pack<<<dim3(4096), dim3(256), 0, stream>>>(qkvb, self_pos, qpk, 0.125f, 3 * kD, 0);
    qk_pack<<<dim3(4096), dim3(256), 0, stream>>>(qkvb, self_pos, kpk, 1.0f, 3 * kD, kD);
    v_pack<<<vgrid, dim3(256), 0, stream>>>(qkvb, vpk, 3 * kD, 2 * kD);
    attn_mfma<<<agrid, dim3(256), 0, stream>>>(qpk, kpk, vpk, self_alibi, mask, attnb);
    gemm(attnb, sa_out_w, sa_out_b, tmp, kTok, kD, kD, 0, 2);
    add_ln<<<dim3(kTok), dim3(256), 0, stream>>>(tgt, tmp, n1_g, n1_b, xb);

    // ---- cross attention ----
    gemm(memory, ca_lat_w, ca_lat_b, proj, kTok, kP, kD, 0, 4);
    gemm(xb, ca_q_w, ca_q_b, qkvb, kTok, kD, kD, 0, 2);          // q into qkvb[0:2M]
    // fused k|v from latent
    transpose_bf16<<<tgD, dim3(256), 0, stream>>>(ca_k_w, wslot, kP, kD);
    transpose_bf16<<<tgD, dim3(256), 0, stream>>>(ca_v_w, wslot + (size_t)kD * kP, kP, kD);
    concat_bias<<<dim3(8), dim3(256), 0, stream>>>(bcat, ca_k_b, ca_v_b, nullptr, kD);
    float* kvb = qkvb + 2 * M1;
    gemm_mfma<<<dim3(2 * kD / 128, kTok / 128, 1), dim3(256), 0, stream>>>(
        proj, wslot, bcat, kvb, kTok, 2 * kD, kP, 0, 1);
    qk_pack<<<dim3(4096), dim3(256), 0, stream>>>(qkvb, cross_pos, qpk, 0.125f, kD, 0);
    qk_pack<<<dim3(4096), dim3(256), 0, stream>>>(kvb, cross_pos, kpk, 1.0f, 2 * kD, 0);
    v_pack<<<vgrid, dim3(256), 0, stream>>>(kvb, vpk, 2 * kD, kD);
    attn_mfma<<<agrid, dim3(256), 0, stream>>>(qpk, kpk, vpk, cross_alibi, mask, attnb);
    gemm(attnb, ca_out_w, ca_out_b, tmp, kTok, kD, kD, 0, 2);
    add_ln<<<dim3(kTok), dim3(256), 0, stream>>>(xb, tmp, n2_g, n2_b, xb);

    // ---- FFN ----
    gemm(xb, lin1_w, lin1_b, ffh, kTok, kFF, kD, 1, 1);
    gemm(ffh, lin2_w, lin2_b, tmp, kTok, kD, kFF, 0, 4);
    ln_final<<<dim3(kTok), dim3(256), 0, stream>>>(xb, tmp, n3_g, n3_b, (float*)d_out);
}

// Round 3
// 673.754 us; speedup vs baseline: 1.2898x; 1.0375x over previous
//
#include <hip/hip_runtime.h>
#include <hip/hip_bf16.h>
#include <math.h>

typedef __hip_bfloat16 hbf16;
typedef __attribute__((ext_vector_type(8))) short bf16x8;
typedef __attribute__((ext_vector_type(4))) float f32x4;

constexpr int kD  = 1024;
constexpr int kP  = 512;
constexpr int kH  = 16;
constexpr int kFF = 4096;
constexpr int kHD = 64;
constexpr int kB  = 2;
constexpr int kL  = 1024;
constexpr int kTok = kB * kL;   // 2048

__device__ inline short f2bf(float x) { hbf16 h = __float2bfloat16(x); return *(short*)&h; }

// ---------------- weight transpose+convert: fp32 [K][N] -> bf16-bits [N][K] ----------------
__global__ __launch_bounds__(256) void transpose_bf16(
    const float* __restrict__ src, short* __restrict__ dst, int K, int N)
{
    __shared__ float t[32][33];
    int n0 = blockIdx.x * 32, k0 = blockIdx.y * 32;
    int tx = threadIdx.x & 31, ty = threadIdx.x >> 5;
    #pragma unroll
    for (int r = ty; r < 32; r += 8)
        t[r][tx] = src[(size_t)(k0 + r) * N + n0 + tx];
    __syncthreads();
    #pragma unroll
    for (int r = ty; r < 32; r += 8)
        dst[(size_t)(n0 + r) * K + k0 + tx] = f2bf(t[tx][r]);
}

// ---------------- bias broadcast fill: C[m][n] = bias[n] (N power of two) ----------------
__global__ __launch_bounds__(256) void bias_fill(
    const float* __restrict__ bias, float* __restrict__ C, int N, int total4)
{
    int i = blockIdx.x * 256 + threadIdx.x;
    if (i >= total4) return;
    int n = (i * 4) & (N - 1);
    *(float4*)&C[(size_t)i * 4] = *(const float4*)&bias[n];
}

// ---------------- concat up to 3 bias vectors of length n ----------------
__global__ void concat_bias(float* __restrict__ o, const float* __restrict__ a,
                            const float* __restrict__ b, const float* __restrict__ c, int n)
{
    int i = blockIdx.x * blockDim.x + threadIdx.x;
    if (i < n) o[i] = a[i];
    else if (i < 2 * n) { if (b) o[i] = b[i - n]; }
    else if (i < 3 * n) { if (c) o[i] = c[i - 2 * n]; }
}

// ---------------- MFMA GEMM with split-K (grid.z) + register prefetch ----------------
constexpr int LDK = 40;
__global__ __launch_bounds__(256) void gemm_mfma(
    const float* __restrict__ A, const short* __restrict__ WT,
    const float* __restrict__ bias, float* __restrict__ C,
    int M, int N, int K, int act, int ksplit)
{
    __shared__ short As[128 * LDK];
    __shared__ short Bs[128 * LDK];
    const int tid = threadIdx.x;
    const int m0 = blockIdx.y * 128, n0 = blockIdx.x * 128;
    const int ks = K / ksplit;
    const int kbeg = blockIdx.z * ks, kend = kbeg + ks;
    const int wave = tid >> 6, lane = tid & 63;
    const int wm = (wave & 1) * 64, wn = (wave >> 1) * 64;
    const int l15 = lane & 15, quad = lane >> 4;

    const int am = tid >> 3, akq = (tid & 7) * 4;
    const int bn = tid >> 2, bkg = (tid & 3) * 8;

    f32x4 acc[4][4];
    #pragma unroll
    for (int i = 0; i < 4; ++i)
        #pragma unroll
        for (int j = 0; j < 4; ++j)
            acc[i][j] = (f32x4){0.f, 0.f, 0.f, 0.f};

    float4 ra[4];
    bf16x8 rb[2];
    #pragma unroll
    for (int e = 0; e < 4; ++e)
        ra[e] = *(const float4*)&A[(size_t)(m0 + am + e * 32) * K + kbeg + akq];
    #pragma unroll
    for (int e = 0; e < 2; ++e)
        rb[e] = *(const bf16x8*)&WT[(size_t)(n0 + bn + e * 64) * K + kbeg + bkg];

    for (int kk = kbeg; kk < kend; kk += 32) {
        #pragma unroll
        for (int e = 0; e < 4; ++e) {
            short4 s4 = make_short4(f2bf(ra[e].x), f2bf(ra[e].y), f2bf(ra[e].z), f2bf(ra[e].w));
            *(short4*)&As[(am + e * 32) * LDK + akq] = s4;
        }
        #pragma unroll
        for (int e = 0; e < 2; ++e)
            *(bf16x8*)&Bs[(bn + e * 64) * LDK + bkg] = rb[e];
        __syncthreads();

        if (kk + 32 < kend) {
            #pragma unroll
            for (int e = 0; e < 4; ++e)
                ra[e] = *(const float4*)&A[(size_t)(m0 + am + e * 32) * K + kk + 32 + akq];
            #pragma unroll
            for (int e = 0; e < 2; ++e)
                rb[e] = *(const bf16x8*)&WT[(size_t)(n0 + bn + e * 64) * K + kk + 32 + bkg];
        }

        bf16x8 af[4], bfr[4];
        #pragma unroll
        for (int i = 0; i < 4; ++i)
            af[i] = *(bf16x8*)&As[(wm + i * 16 + l15) * LDK + quad * 8];
        #pragma unroll
        for (int j = 0; j < 4; ++j)
            bfr[j] = *(bf16x8*)&Bs[(wn + j * 16 + l15) * LDK + quad * 8];
        #pragma unroll
        for (int i = 0; i < 4; ++i)
            #pragma unroll
            for (int j = 0; j < 4; ++j)
                acc[i][j] = __builtin_amdgcn_mfma_f32_16x16x32_bf16(af[i], bfr[j], acc[i][j], 0, 0, 0);
        __syncthreads();
    }

    #pragma unroll
    for (int j = 0; j < 4; ++j) {
        int n = n0 + wn + j * 16 + l15;
        if (ksplit == 1) {
            float bv = bias[n];
            #pragma unroll
            for (int i = 0; i < 4; ++i) {
                int mb = m0 + wm + i * 16 + quad * 4;
                #pragma unroll
                for (int r = 0; r < 4; ++r) {
                    float v = acc[i][j][r] + bv;
                    if (act) v = v * 0.5f * (1.0f + erff(v * 0.70710678118654752f));
                    C[(size_t)(mb + r) * N + n] = v;
                }
            }
        } else {
            #pragma unroll
            for (int i = 0; i < 4; ++i) {
                int mb = m0 + wm + i * 16 + quad * 4;
                #pragma unroll
                for (int r = 0; r < 4; ++r)
                    atomicAdd(&C[(size_t)(mb + r) * N + n], acc[i][j][r]);
            }
        }
    }
}

// ---------------- qk_pack: RoPE + optional scale + bf16 cast, [Tok,ldx] -> [b,h,l,64] ----------------
__global__ void qk_pack(const float* __restrict__ x, const float* __restrict__ pos,
                        short* __restrict__ outp, float scale, int ldx, int off)
{
    int idx = blockIdx.x * blockDim.x + threadIdx.x;
    if (idx >= kTok * kH * 32) return;
    int d = idx & 31;
    int h = (idx >> 5) & (kH - 1);
    int row = idx >> 9;
    int l = row & (kL - 1);
    int b = row >> 10;
    float a1 = pos[l * kHD + d];
    float a2 = pos[l * kHD + d + 32];
    size_t base = (size_t)row * ldx + off + h * kHD;
    float x1 = x[base + d], x2 = x[base + d + 32];
    float r1 = (x1 * cosf(a1) - x2 * sinf(a1)) * scale;
    float r2 = (x2 * cosf(a2) + x1 * sinf(a2)) * scale;
    size_t ob = ((size_t)(b * kH + h) * kL + l) * 64;
    outp[ob + d]      = f2bf(r1);
    outp[ob + d + 32] = f2bf(r2);
}

// ---------------- v_pack: transpose [Tok,ldx] fp32 -> [b,h,hd,l] bf16 ----------------
__global__ __launch_bounds__(256) void v_pack(const float* __restrict__ v, short* __restrict__ outp,
                                              int ldx, int off)
{
    int l0 = blockIdx.x * 64, h = blockIdx.y, b = blockIdx.z;
    __shared__ float t[64][65];
    int tid = threadIdx.x;
    #pragma unroll
    for (int e = 0; e < 4; ++e) {
        int idx = tid + e * 256;
        int r = idx >> 4, c4 = (idx & 15) * 4;
        const float4 vv = *(const float4*)&v[(size_t)(b * kL + l0 + r) * ldx + off + h * kHD + c4];
        t[r][c4] = vv.x; t[r][c4 + 1] = vv.y; t[r][c4 + 2] = vv.z; t[r][c4 + 3] = vv.w;
    }
    __syncthreads();
    int hd = tid >> 2, seg = (tid & 3) * 16;
    size_t ob = ((size_t)(b * kH + h) * 64 + hd) * kL + l0 + seg;
    short tmp[16];
    #pragma unroll
    for (int i = 0; i < 16; ++i) tmp[i] = f2bf(t[seg + i][hd]);
    #pragma unroll
    for (int i = 0; i < 16; i += 4)
        *(short4*)&outp[ob + i] = make_short4(tmp[i], tmp[i + 1], tmp[i + 2], tmp[i + 3]);
}

// ---------------- MFMA flash attention (fragment-ordered LDS, staged alibi) ----------------
// block = (b, h, 64 q-rows); 4 waves x 16 q-rows; 64-key tiles; online softmax in registers.
// LDS: Qf/Kf/Vf in MFMA fragment order (conflict-free b128 reads).
//   frag slot(r,c) = ((r>>4)*2 + (c>>5))*512 + (r&15)*32 + ((c>>3)&3)*8   [shorts]
// ALPS: union of alibi tile (stride 68, rows 16w..16w+15 == wave slab w) and
//       per-wave P slab (wave*1088 + row*67 + key) — intra-wave reuse, no extra barrier.
constexpr int AQ = 64, AK = 64;
__global__ __launch_bounds__(256, 2) void attn_mfma(
    const short* __restrict__ qpk, const short* __restrict__ kpk,
    const short* __restrict__ vpk, const float* __restrict__ alibi,
    const int* __restrict__ mask, float* __restrict__ out)
{
    const int q0 = blockIdx.x * AQ, h = blockIdx.y, b = blockIdx.z;
    const int tid = threadIdx.x, wave = tid >> 6, lane = tid & 63;
    const int l15 = lane & 15, quad = lane >> 4;
    __shared__ short Qf[4096];
    __shared__ short Kf[4096];
    __shared__ short Vf[4096];
    __shared__ float ALPS[4 * 1088];

    const short* qbase = qpk + ((size_t)(b * kH + h) * kL) * 64;
    const short* kbase = kpk + ((size_t)(b * kH + h) * kL) * 64;
    const short* vbase = vpk + ((size_t)(b * kH + h) * 64) * kL;
    const float* abase = alibi + ((size_t)h * kL + q0) * kL;
    const int*   mbase = mask + b * kL;

    // staging coords: rows sr, sr+32; 8 shorts at col sc8
    const int sr = tid >> 3, sc8 = (tid & 7) * 8;
    const int sQuad = (sc8 >> 3) & 3, sS = sc8 >> 5;
    // alibi staging coords: rows ar + e*16, float4 at col ac4
    const int ar = tid >> 4, ac4 = (tid & 15) * 4;

    // stage Q once (fragment order)
    #pragma unroll
    for (int e = 0; e < 2; ++e) {
        int r = sr + e * 32;
        int slot = ((r >> 4) * 2 + sS) * 512 + (r & 15) * 32 + sQuad * 8;
        *(bf16x8*)&Qf[slot] = *(const bf16x8*)&qbase[(size_t)(q0 + r) * 64 + sc8];
    }

    // prefetch registers for K/V/alibi/mask of the next tile
    bf16x8 rk[2], rv[2];
    float4 ral[4];
    int4 rmk;
    auto load_tile = [&](int k0) {
        #pragma unroll
        for (int e = 0; e < 2; ++e) {
            int r = sr + e * 32;
            rk[e] = *(const bf16x8*)&kbase[(size_t)(k0 + r) * 64 + sc8];
            rv[e] = *(const bf16x8*)&vbase[(size_t)r * kL + k0 + sc8];
        }
        #pragma unroll
        for (int e = 0; e < 4; ++e)
            ral[e] = *(const float4*)&abase[(size_t)(ar + e * 16) * kL + k0 + ac4];
        rmk = *(const int4*)&mbase[k0 + ac4];
    };
    auto store_tile = [&]() {
        #pragma unroll
        for (int e = 0; e < 2; ++e) {
            int r = sr + e * 32;
            int slot = ((r >> 4) * 2 + sS) * 512 + (r & 15) * 32 + sQuad * 8;
            *(bf16x8*)&Kf[slot] = rk[e];
            *(bf16x8*)&Vf[slot] = rv[e];
        }
        #pragma unroll
        for (int e = 0; e < 4; ++e) {
            float4 a = ral[e];
            a.x = rmk.x ? -1e30f : a.x;
            a.y = rmk.y ? -1e30f : a.y;
            a.z = rmk.z ? -1e30f : a.z;
            a.w = rmk.w ? -1e30f : a.w;
            *(float4*)&ALPS[(ar + e * 16) * 68 + ac4] = a;
        }
    };

    float mst[4], lst[4];
    #pragma unroll
    for (int r = 0; r < 4; ++r) { mst[r] = -3e38f; lst[r] = 0.f; }
    f32x4 oacc[4];
    #pragma unroll
    for (int j = 0; j < 4; ++j) oacc[j] = (f32x4){0.f, 0.f, 0.f, 0.f};

    load_tile(0);
    __syncthreads();   // Q visible to all waves

    // Q fragments are tile-invariant: hoist out of the k-loop
    bf16x8 aq[2];
    #pragma unroll
    for (int s = 0; s < 2; ++s)
        aq[s] = *(bf16x8*)&Qf[(wave * 2 + s) * 512 + l15 * 32 + quad * 8];

    for (int t = 0; t < kL / AK; ++t) {
        store_tile();
        __syncthreads();   // staging visible
        if (t + 1 < kL / AK) load_tile((t + 1) * AK);

        // ---- S = Q K^T ----
        f32x4 sacc[4];
        #pragma unroll
        for (int nt = 0; nt < 4; ++nt) sacc[nt] = (f32x4){0.f, 0.f, 0.f, 0.f};
        #pragma unroll
        for (int nt = 0; nt < 4; ++nt)
            #pragma unroll
            for (int s = 0; s < 2; ++s) {
                bf16x8 bk = *(bf16x8*)&Kf[(nt * 2 + s) * 512 + l15 * 32 + quad * 8];
                sacc[nt] = __builtin_amdgcn_mfma_f32_16x16x32_bf16(aq[s], bk, sacc[nt], 0, 0, 0);
            }

        // ---- epilogue: + (masked) alibi from LDS; online softmax in registers ----
        float sv[4][4];
        float mx[4] = {-3e38f, -3e38f, -3e38f, -3e38f};
        #pragma unroll
        for (int nt = 0; nt < 4; ++nt)
            #pragma unroll
            for (int r = 0; r < 4; ++r) {
                float al = ALPS[(wave * 16 + quad * 4 + r) * 68 + nt * 16 + l15];
                float s = sacc[nt][r] + al;
                sv[nt][r] = s;
                mx[r] = fmaxf(mx[r], s);
            }
        #pragma unroll
        for (int m = 1; m <= 8; m <<= 1)
            #pragma unroll
            for (int r = 0; r < 4; ++r)
                mx[r] = fmaxf(mx[r], __shfl_xor(mx[r], m));
        float alpha[4], lsum[4];
        #pragma unroll
        for (int r = 0; r < 4; ++r) {
            float mn = fmaxf(mst[r], mx[r]);
            alpha[r] = __expf(mst[r] - mn);
            mst[r] = mn;
            lsum[r] = 0.f;
        }
        #pragma unroll
        for (int nt = 0; nt < 4; ++nt)
            #pragma unroll
            for (int r = 0; r < 4; ++r) {
                float p = __expf(sv[nt][r] - mst[r]);
                sv[nt][r] = p;
                lsum[r] += p;
            }
        #pragma unroll
        for (int m = 1; m <= 8; m <<= 1)
            #pragma unroll
            for (int r = 0; r < 4; ++r)
                lsum[r] += __shfl_xor(lsum[r], m);
        #pragma unroll
        for (int r = 0; r < 4; ++r) lst[r] = lst[r] * alpha[r] + lsum[r];

        // write P into the wave's private slab (stride 67 -> 2-way-free scalar reads)
        #pragma unroll
        for (int nt = 0; nt < 4; ++nt)
            #pragma unroll
            for (int r = 0; r < 4; ++r)
                ALPS[wave * 1088 + (quad * 4 + r) * 67 + nt * 16 + l15] = sv[nt][r];
        #pragma unroll
        for (int j = 0; j < 4; ++j)
            #pragma unroll
            for (int r = 0; r < 4; ++r)
                oacc[j][r] *= alpha[r];

        // ---- O += P V (P round-trip is intra-wave: no barrier needed) ----
        #pragma unroll
        for (int s = 0; s < 2; ++s) {
            int pb = wave * 1088 + l15 * 67 + s * 32 + quad * 8;
            bf16x8 ap;
            #pragma unroll
            for (int e = 0; e < 8; ++e) ap[e] = f2bf(ALPS[pb + e]);
            #pragma unroll
            for (int j = 0; j < 4; ++j) {
                bf16x8 bv = *(bf16x8*)&Vf[(j * 2 + s) * 512 + l15 * 32 + quad * 8];
                oacc[j] = __builtin_amdgcn_mfma_f32_16x16x32_bf16(ap, bv, oacc[j], 0, 0, 0);
            }
        }
        __syncthreads();   // all reads done before next store_tile
    }

    #pragma unroll
    for (int j = 0; j < 4; ++j)
        #pragma unroll
        for (int r = 0; r < 4; ++r) {
            int qrow = q0 + wave * 16 + quad * 4 + r;
            out[(size_t)(b * kL + qrow) * kD + h * kHD + j * 16 + l15] = oacc[j][r] / lst[r];
        }
}

// ---------------- out = res + LayerNorm(z) ----------------
__global__ __launch_bounds__(256) void add_ln(
    const float* __restrict__ res, const float* __restrict__ z,
    const float* __restrict__ g, const float* __restrict__ bi,
    float* __restrict__ out)
{
    int row = blockIdx.x, tid = threadIdx.x;
    __shared__ float red[256], red2[256];
    const float* zr = z + (size_t)row * kD;
    float s = 0.f, sq = 0.f;
    for (int i = tid; i < kD; i += 256) { float vv = zr[i]; s += vv; sq += vv * vv; }
    red[tid] = s; red2[tid] = sq; __syncthreads();
    for (int st = 128; st > 0; st >>= 1) {
        if (tid < st) { red[tid] += red[tid + st]; red2[tid] += red2[tid + st]; }
        __syncthreads();
    }
    float mean = red[0] / kD;
    float var = red2[0] / kD - mean * mean;
    float rstd = rsqrtf(var + 1e-5f);
    for (int i = tid; i < kD; i += 256) {
        float vv = (zr[i] - mean) * rstd * g[i] + bi[i];
        out[(size_t)row * kD + i] = res[(size_t)row * kD + i] + vv;
    }
}

// ---------------- out = LayerNorm(res + f) ----------------
__global__ __launch_bounds__(256) void ln_final(
    const float* __restrict__ res, const float* __restrict__ f,
    const float* __restrict__ g, const float* __restrict__ bi,
    float* __restrict__ out)
{
    int row = blockIdx.x, tid = threadIdx.x;
    __shared__ float tt[kD];
    __shared__ float red[256], red2[256];
    float s = 0.f, sq = 0.f;
    for (int i = tid; i < kD; i += 256) {
        float vv = res[(size_t)row * kD + i] + f[(size_t)row * kD + i];
        tt[i] = vv; s += vv; sq += vv * vv;
    }
    red[tid] = s; red2[tid] = sq; __syncthreads();
    for (int st = 128; st > 0; st >>= 1) {
        if (tid < st) { red[tid] += red[tid + st]; red2[tid] += red2[tid + st]; }
        __syncthreads();
    }
    float mean = red[0] / kD;
    float var = red2[0] / kD - mean * mean;
    float rstd = rsqrtf(var + 1e-5f);
    for (int i = tid; i < kD; i += 256)
        out[(size_t)row * kD + i] = (tt[i] - mean) * rstd * g[i] + bi[i];
}

extern "C" void kernel_launch(void* const* d_in, const int* in_sizes, int n_in,
                              void* d_out, int out_size, void* d_ws, size_t ws_size,
                              hipStream_t stream)
{
    const float* memory      = (const float*)d_in[0];
    const float* tgt         = (const float*)d_in[1];
    const float* self_alibi  = (const float*)d_in[2];
    const float* self_pos    = (const float*)d_in[3];
    const float* cross_alibi = (const float*)d_in[4];
    const float* cross_pos   = (const float*)d_in[5];
    const int*   mask        = (const int*)d_in[6];
    const float* sa_lat_w = (const float*)d_in[7];   const float* sa_lat_b = (const float*)d_in[8];
    const float* sa_q_w   = (const float*)d_in[9];   const float* sa_q_b   = (const float*)d_in[10];
    const float* sa_k_w   = (const float*)d_in[11];  const float* sa_k_b   = (const float*)d_in[12];
    const float* sa_v_w   = (const float*)d_in[13];  const float* sa_v_b   = (const float*)d_in[14];
    const float* sa_out_w = (const float*)d_in[15];  const float* sa_out_b = (const float*)d_in[16];
    const float* ca_lat_w = (const float*)d_in[17];  const float* ca_lat_b = (const float*)d_in[18];
    const float* ca_q_w   = (const float*)d_in[19];  const float* ca_q_b   = (const float*)d_in[20];
    const float* ca_k_w   = (const float*)d_in[21];  const float* ca_k_b   = (const float*)d_in[22];
    const float* ca_v_w   = (const float*)d_in[23];  const float* ca_v_b   = (const float*)d_in[24];
    const float* ca_out_w = (const float*)d_in[25];  const float* ca_out_b = (const float*)d_in[26];
    const float* lin1_w   = (const float*)d_in[27];  const float* lin1_b   = (const float*)d_in[28];
    const float* lin2_w   = (const float*)d_in[29];  const float* lin2_b   = (const float*)d_in[30];
    const float* n1_g = (const float*)d_in[31];  const float* n1_b = (const float*)d_in[32];
    const float* n2_g = (const float*)d_in[33];  const float* n2_b = (const float*)d_in[34];
    const float* n3_g = (const float*)d_in[35];  const float* n3_b = (const float*)d_in[36];

    // workspace: 15M floats = 60 MB (same footprint as before)
    const size_t M1 = 1u << 20;
    float* W     = (float*)d_ws;
    float* xb    = W + 0 * M1;    // 2M — residual stream
    float* tmp   = W + 2 * M1;    // 2M — pre-LN tensor (free during attention)
    float* proj  = W + 4 * M1;    // 1M — latent projection
    float* qkvb  = W + 5 * M1;    // 6M — fused qkv [2048][3072]; cross: qb=+0 (2M), kvb=+2M (4M)
    float* attnb = W + 11 * M1;   // 2M
    float* ffh   = W + 4 * M1;    // 8M — FFN hidden, overlays proj/qkvb/attnb-low
    short* wslot = (short*)(W + 13 * M1);  // 4M shorts
    float* bcat  = W + 11 * M1;   // bias concat scratch (attnb region, dead at use time)
    // packed bf16 buffers overlay dead fp32 regions during attention:
    short* qpk = (short*)(W + 2 * M1);   // 2M shorts over tmp[0:1M]
    short* kpk = (short*)(W + 3 * M1);   // 2M shorts over tmp[1M:2M]
    short* vpk = (short*)(W + 4 * M1);   // 2M shorts over proj (dead after kv gemm)

    auto gemm = [&](const float* A, const float* Wt, const float* bias, float* C,
                    int M, int N, int K, int act, int S) {
        transpose_bf16<<<dim3(N / 32, K / 32), dim3(256), 0, stream>>>(Wt, wslot, K, N);
        if (S > 1)
            bias_fill<<<dim3(M * N / 1024), dim3(256), 0, stream>>>(bias, C, N, M * N / 4);
        gemm_mfma<<<dim3(N / 128, M / 128, S), dim3(256), 0, stream>>>(A, wslot, bias, C, M, N, K, act, S);
    };
    dim3 agrid(kL / AQ, kH, kB);
    dim3 vgrid(kL / 64, kH, kB);
    dim3 tgD(kD / 32, kP / 32);   // transpose grid for [kP][kD] weights

    // ---- self attention ----
    gemm(tgt, sa_lat_w, sa_lat_b, proj, kTok, kP, kD, 0, 4);
    // fused q|k|v: WT rows [0,1024)=q, [1024,2048)=k, [2048,3072)=v
    transpose_bf16<<<tgD, dim3(256), 0, stream>>>(sa_q_w, wslot, kP, kD);
    transpose_bf16<<<tgD, dim3(256), 0, stream>>>(sa_k_w, wslot + (size_t)kD * kP, kP, kD);
    transpose_bf16<<<tgD, dim3(256), 0, stream>>>(sa_v_w, wslot + (size_t)2 * kD * kP, kP, kD);
    concat_bias<<<dim3(12), dim3(256), 0, stream>>>(bcat, sa_q_b, sa_k_b, sa_v_b, kD);
    gemm_mfma<<<dim3(3 * kD / 128, kTok / 128, 1), dim3(256), 0, stream>>>(
        proj, wslot, bcat, qkvb, kTok, 3 * kD, kP, 0, 1);
    qk_pack<<<dim3(4096), dim3(256), 0, stream>>>(qkvb, self_pos, qpk, 0.125f, 3 * kD, 0);
    qk_pack<<<dim3(4096), dim3(256), 0, stream>>>(qkvb, self_pos, kpk, 1.0f, 3 * kD, kD);
    v_pack<<<vgrid, dim3(256), 0, stream>>>(qkvb, vpk, 3 * kD, 2 * kD);
    attn_mfma<<<agrid, dim3(256), 0, stream>>>(qpk, kpk, vpk, self_alibi, mask, attnb);
    gemm(attnb, sa_out_w, sa_out_b, tmp, kTok, kD, kD, 0, 2);
    add_ln<<<dim3(kTok), dim3(256), 0, stream>>>(tgt, tmp, n1_g, n1_b, xb);

    // ---- cross attention ----
    gemm(memory, ca_lat_w, ca_lat_b, proj, kTok, kP, kD, 0, 4);
    gemm(xb, ca_q_w, ca_q_b, qkvb, kTok, kD, kD, 0, 2);          // q into qkvb[0:2M]
    // fused k|v from latent
    transpose_bf16<<<tgD, dim3(256), 0, stream>>>(ca_k_w, wslot, kP, kD);
    transpose_bf16<<<tgD, dim3(256), 0, stream>>>(ca_v_w, wslot + (size_t)kD * kP, kP, kD);
    concat_bias<<<dim3(8), dim3(256), 0, stream>>>(bcat, ca_k_b, ca_v_b, nullptr, kD);
    float* kvb = qkvb + 2 * M1;
    gemm_mfma<<<dim3(2 * kD / 128, kTok / 128, 1), dim3(256), 0, stream>>>(
        proj, wslot, bcat, kvb, kTok, 2 * kD, kP, 0, 1);
    qk_pack<<<dim3(4096), dim3(256), 0, stream>>>(qkvb, cross_pos, qpk, 0.125f, kD, 0);
    qk_pack<<<dim3(4096), dim3(256), 0, stream>>>(kvb, cross_pos, kpk, 1.0f, 2 * kD, 0);
    v_pack<<<vgrid, dim3(256), 0, stream>>>(kvb, vpk, 2 * kD, kD);
    attn_mfma<<<agrid, dim3(256), 0, stream>>>(qpk, kpk, vpk, cross_alibi, mask, attnb);
    gemm(attnb, ca_out_w, ca_out_b, tmp, kTok, kD, kD, 0, 2);
    add_ln<<<dim3(kTok), dim3(256), 0, stream>>>(xb, tmp, n2_g, n2_b, xb);

    // ---- FFN ----
    gemm(xb, lin1_w, lin1_b, ffh, kTok, kFF, kD, 1, 1);
    gemm(ffh, lin2_w, lin2_b, tmp, kTok, kD, kFF, 0, 4);
    ln_final<<<dim3(kTok), dim3(256), 0, stream>>>(xb, tmp, n3_g, n3_b, (float*)d_out);
}